// Round 5
// baseline (618.398 us; speedup 1.0000x reference)
//
#include <hip/hip_runtime.h>
#include <math.h>

// WindowAttention fused kernel, round 5.
// vs round 4 (356us/dispatch, MfmaUtil 19, VALUBusy 53):
// - comb[w][h][mt][ntt][lane][ri] = mask + pos_bias precomputed in MFMA
//   fragment order (67MB static __device__), padding baked in. Phase 2's
//   64 scalar gathers/thread -> 8 coalesced float4 loads.
// - Phase-1 qkv weight-frag loads software-pipelined (ping-pong, first set
//   issued before the phase-0 barrier).
// - Phase-4 proj-W frag loads hoisted to phase-3 top (drain at barrier).
//
// Fragment conventions (sigma-consistent A/B slot->k maps, D per m89):
//   A: row = lane&15, slot(g=lane>>4, j) -> k = 8g+j
//   B: col = lane&15, same slot map
//   D: col = lane&15, row = 4*(lane>>4)+reg
// Unit = 64 lanes x 16B = 1KB.
//
// LDS (65536 B): XU 16K (x-frags -> u-frags) | Qr 16K (q) | Kr 16K (k) |
//                Vr 16K (v-frags); P-frags overwrite Qr+Kr.

namespace {
constexpr int N  = 49;
constexpr int C  = 128;
constexpr int NT = 512;
constexpr int NWMAX = 1024;
constexpr float SCALE = 0.17677669529663687f;  // 32^-0.5

typedef short bf16x8 __attribute__((ext_vector_type(8)));
typedef float f32x4  __attribute__((ext_vector_type(4)));
}

// ---- static device storage for block-invariant data ----
__device__ __align__(16) ushort g_wq_hi[24 * 4 * 512];   //  96 KB qkv W hi-frags
__device__ __align__(16) ushort g_wq_lo[24 * 4 * 512];   //  96 KB qkv W lo-frags
__device__ __align__(16) ushort g_wp_hi[8 * 4 * 512];    //  32 KB proj W hi-frags
__device__ __align__(16) ushort g_wp_lo[8 * 4 * 512];    //  32 KB proj W lo-frags
// comb[w][h][mt][ntt][lane][ri] = mask[w][n][m] + pos_bias[h][n][m], frag order
__device__ __align__(16) float  g_comb[NWMAX * 4 * 4 * 4 * 256];   // 67 MB

__device__ __forceinline__ ushort bf16_rne(float f) {
    unsigned int u = __builtin_bit_cast(unsigned int, f);
    unsigned int r = u + 0x7FFFu + ((u >> 16) & 1u);
    return (ushort)(r >> 16);
}
__device__ __forceinline__ float bf16_to_f(ushort h) {
    unsigned int u = ((unsigned int)h) << 16;
    return __builtin_bit_cast(float, u);
}
__device__ __forceinline__ void split2(float x, ushort& hi, ushort& lo) {
    hi = bf16_rne(x);
    lo = bf16_rne(x - bf16_to_f(hi));
}
__device__ __forceinline__ f32x4 mfma16(bf16x8 a, bf16x8 b, f32x4 c) {
    return __builtin_amdgcn_mfma_f32_16x16x32_bf16(a, b, c, 0, 0, 0);
}
// 16B-slot index within a 1KB unit, XOR-rotate swizzled (phase-0 write spread).
__device__ __forceinline__ int idx16(int row, int g, int ks) {
    return ((row + 4 * g + ks) & 15) + 16 * g;
}

// ---- prep kernel: block-invariant conversions ----
__global__ void prep(const float* __restrict__ qkv_w, const float* __restrict__ proj_w,
                     const float* __restrict__ table, const int* __restrict__ pos_index,
                     const float* __restrict__ mask, int nW)
{
    const int i = blockIdx.x * 256 + threadIdx.x;
    if (i < 24 * 4 * 512) {   // qkv B-frags
        const int unit = i >> 9, sl = i & 511;
        const int nt = unit >> 2, ks = unit & 3;
        const int lane = sl >> 3, j = sl & 7;
        const float w = qkv_w[(nt * 16 + (lane & 15)) * C + ks * 32 + (lane >> 4) * 8 + j];
        ushort hi, lo; split2(w, hi, lo);
        g_wq_hi[i] = hi; g_wq_lo[i] = lo;
    }
    if (i < 8 * 4 * 512) {    // proj B-frags
        const int unit = i >> 9, sl = i & 511;
        const int nt = unit >> 2, ks = unit & 3;
        const int lane = sl >> 3, j = sl & 7;
        const float w = proj_w[(nt * 16 + (lane & 15)) * C + ks * 32 + (lane >> 4) * 8 + j];
        ushort hi, lo; split2(w, hi, lo);
        g_wp_hi[i] = hi; g_wp_lo[i] = lo;
    }
    // comb fill: one thread per float4 (over ri)
    const int NC4 = nW * 4 * 4 * 4 * 64;
    if (i < NC4) {
        const int lane = i & 63;
        const int ntt  = (i >> 6) & 3;
        const int mt   = (i >> 8) & 3;
        const int h    = (i >> 10) & 3;
        const int w    = i >> 12;
        const int m    = ntt * 16 + (lane & 15);
        float vv[4];
        #pragma unroll
        for (int ri = 0; ri < 4; ++ri) {
            const int n0 = mt * 16 + (lane >> 4) * 4 + ri;
            const int n  = n0 > 48 ? 48 : n0;
            if (m < 49) {
                const int rr = n * 49 + m;
                vv[ri] = mask[w * 2401 + rr] + table[pos_index[rr] * 4 + h];
            } else {
                vv[ri] = -1e30f;   // pad cols -> softmax zero
            }
        }
        *((float4*)g_comb + i) = make_float4(vv[0], vv[1], vv[2], vv[3]);
    }
}

__device__ __forceinline__ void load_wq(bf16x8* bh, bf16x8* bl, int nt, int lane) {
    #pragma unroll
    for (int ks = 0; ks < 4; ++ks) {
        bh[ks] = *(const bf16x8*)(g_wq_hi + (nt * 4 + ks) * 512 + lane * 8);
        bl[ks] = *(const bf16x8*)(g_wq_lo + (nt * 4 + ks) * 512 + lane * 8);
    }
}

// One qkv column-tile step: 16 ds_read_b128 + 32 MFMA + scatter to q/k/v frags.
__device__ __forceinline__ void qkv_step(
    int nt, const bf16x8* bh, const bf16x8* bl,
    const unsigned char* XU, unsigned char* Qr, unsigned char* Kr, unsigned char* Vr,
    int lane, int lr, int lg)
{
    const f32x4 fz = {0.f, 0.f, 0.f, 0.f};
    f32x4 acc[4] = {fz, fz, fz, fz};
    #pragma unroll
    for (int ks = 0; ks < 4; ++ks) {
        #pragma unroll
        for (int mt = 0; mt < 4; ++mt) {
            const bf16x8 ah = *(const bf16x8*)(XU + (mt * 4 + ks) * 1024
                                                  + idx16(lr, lg, ks) * 16);
            acc[mt] = mfma16(ah, bl[ks], acc[mt]);
            acc[mt] = mfma16(ah, bh[ks], acc[mt]);
        }
    }
    const int o   = nt * 16 + lr;
    const int sec = o >> 7;          // 0=q 1=k 2=v (wave-uniform)
    const int h   = (o >> 5) & 3;
    const int d   = o & 31;
    #pragma unroll
    for (int mt = 0; mt < 4; ++mt) {
        unsigned int hh[4];
        #pragma unroll
        for (int ri = 0; ri < 4; ++ri) {
            float v0 = acc[mt][ri];
            if (sec == 0) v0 *= SCALE;
            hh[ri] = (unsigned int)bf16_rne(v0);
        }
        if (sec <= 1) {
            unsigned char* ubase = (sec == 0 ? Qr : Kr) + (h * 4 + mt) * 1024;
            #pragma unroll
            for (int ri = 0; ri < 4; ++ri) {
                const unsigned int part = __shfl_xor(hh[ri], 1);
                if (!(lane & 1)) {
                    const int n = mt * 16 + lg * 4 + ri;
                    *(unsigned int*)(ubase + ((n & 15) + 16 * (d >> 3)) * 16
                                           + (d & 7) * 2) = hh[ri] | (part << 16);
                }
            }
        } else {
            #pragma unroll
            for (int rp = 0; rp < 2; ++rp) {   // pack (ri, ri+1): adjacent k=n
                const int n = mt * 16 + lg * 4 + rp * 2;
                const int u = (h * 2 + (d >> 4)) * 2 + (n >> 5);
                *(unsigned int*)(Vr + u * 1024 + ((d & 15) + 16 * ((n & 31) >> 3)) * 16
                                    + (n & 7) * 2) = hh[rp * 2] | (hh[rp * 2 + 1] << 16);
            }
        }
    }
}

__global__ __launch_bounds__(NT, 4) void win_attn(
    const float* __restrict__ x,         // [B,49,128]
    const float* __restrict__ proj_b,    // [128]
    float* __restrict__ out,             // [B,49,128]
    int nW)
{
    __shared__ __align__(16) unsigned char smem[65536];
    unsigned char* const XU = smem;            // 16KB x-frags -> u-frags
    unsigned char* const Qr = smem + 16384;    // 16KB q-frags
    unsigned char* const Kr = smem + 32768;    // 16KB k-frags
    unsigned char* const Vr = smem + 49152;    // 16KB v-frags
    unsigned char* const Pr = smem + 16384;    // 32KB P-frags (over Qr+Kr)

    const int tid  = threadIdx.x;
    const int blk  = blockIdx.x;
    const int lane = tid & 63;
    const int wid  = tid >> 6;
    const int lr   = lane & 15;
    const int lg   = lane >> 4;
    const f32x4 fz = {0.f, 0.f, 0.f, 0.f};

    // ---- Phase 0: x -> A-frags (bf16 hi), rows 49..63 zero ----
    {
        const float* xb = x + (size_t)blk * (N * C);
        #pragma unroll
        for (int it = 0; it < 2; ++it) {
            const int slot = tid + it * NT;   // (n 0..63) x (chunk 0..15)
            const int n  = slot >> 4;
            const int cc = slot & 15;
            const int s  = cc >> 2;           // ks
            const int g  = cc & 3;            // k-group
            unsigned int h32[4];
            if (n < N) {
                const float4 f0 = *(const float4*)(xb + n * C + cc * 8);
                const float4 f1 = *(const float4*)(xb + n * C + cc * 8 + 4);
                const float f[8] = {f0.x, f0.y, f0.z, f0.w, f1.x, f1.y, f1.z, f1.w};
                #pragma unroll
                for (int j = 0; j < 4; ++j)
                    h32[j] = (unsigned int)bf16_rne(f[2*j])
                           | ((unsigned int)bf16_rne(f[2*j+1]) << 16);
            } else {
                #pragma unroll
                for (int j = 0; j < 4; ++j) h32[j] = 0u;
            }
            unsigned char* p = XU + ((n >> 4) * 4 + s) * 1024 + idx16(n & 15, g, s) * 16;
            *(uint4*)p = make_uint4(h32[0], h32[1], h32[2], h32[3]);
        }
    }
    // issue t=0 weight-frag loads before the barrier (overlap with staging)
    bf16x8 bhA[4], blA[4], bhB[4], blB[4];
    load_wq(bhA, blA, wid, lane);
    __syncthreads();

    // ---- Phase 1: qkv GEMM, software-pipelined over 3 column-tiles ----
    load_wq(bhB, blB, wid + 8, lane);                      // prefetch t=1
    qkv_step(wid,      bhA, blA, XU, Qr, Kr, Vr, lane, lr, lg);
    load_wq(bhA, blA, wid + 16, lane);                     // prefetch t=2
    qkv_step(wid + 8,  bhB, blB, XU, Qr, Kr, Vr, lane, lr, lg);
    qkv_step(wid + 16, bhA, blA, XU, Qr, Kr, Vr, lane, lr, lg);
    __syncthreads();

    // ---- Phase 2: scores (MFMA) + precombined bias/mask + in-reg softmax ----
    float Ps[2][4][4];
    {
        const float* cbase = g_comb + (size_t)(blk % nW) * (4 * 4 * 4 * 256);
        #pragma unroll
        for (int pass = 0; pass < 2; ++pass) {
            const int cb = wid + pass * 8;   // (head, row-tile)
            const int h = cb >> 2, mt = cb & 3;
            const float* chm = cbase + (h * 4 + mt) * 1024;
            float4 cv[4];
            #pragma unroll
            for (int ntt = 0; ntt < 4; ++ntt)
                cv[ntt] = *(const float4*)(chm + ntt * 256 + lane * 4);
            const bf16x8 qh = *(const bf16x8*)(Qr + (h * 4 + mt) * 1024 + lane * 16);
            f32x4 S[4];
            #pragma unroll
            for (int ntt = 0; ntt < 4; ++ntt) {
                const bf16x8 kh = *(const bf16x8*)(Kr + (h * 4 + ntt) * 1024 + lane * 16);
                S[ntt] = mfma16(qh, kh, fz);
            }
            #pragma unroll
            for (int ntt = 0; ntt < 4; ++ntt) {
                S[ntt][0] += cv[ntt].x;
                S[ntt][1] += cv[ntt].y;
                S[ntt][2] += cv[ntt].z;
                S[ntt][3] += cv[ntt].w;
            }
            #pragma unroll
            for (int ri = 0; ri < 4; ++ri) {
                float mx = fmaxf(fmaxf(S[0][ri], S[1][ri]), fmaxf(S[2][ri], S[3][ri]));
                mx = fmaxf(mx, __shfl_xor(mx, 1));
                mx = fmaxf(mx, __shfl_xor(mx, 2));
                mx = fmaxf(mx, __shfl_xor(mx, 4));
                mx = fmaxf(mx, __shfl_xor(mx, 8));
                float sm = 0.f;
                #pragma unroll
                for (int ntt = 0; ntt < 4; ++ntt) {
                    const float e = __expf(S[ntt][ri] - mx);
                    Ps[pass][ntt][ri] = e;
                    sm += e;
                }
                sm += __shfl_xor(sm, 1);
                sm += __shfl_xor(sm, 2);
                sm += __shfl_xor(sm, 4);
                sm += __shfl_xor(sm, 8);
                const float pinv = 1.f / sm;   // fold 1/sum into P
                #pragma unroll
                for (int ntt = 0; ntt < 4; ++ntt) Ps[pass][ntt][ri] *= pinv;
            }
        }
    }
    __syncthreads();   // q/k reads done before P overwrites

    // ---- Phase 2b: write normalized P as A-frags over Qr+Kr ----
    {
        #pragma unroll
        for (int pass = 0; pass < 2; ++pass) {
            const int cb = wid + pass * 8;
            const int h = cb >> 2, mt = cb & 3;
            #pragma unroll
            for (int ntt = 0; ntt < 4; ++ntt) {
                const int m = ntt * 16 + lr;   // k-index
                #pragma unroll
                for (int ri = 0; ri < 4; ++ri) {
                    const unsigned int hh = (unsigned int)bf16_rne(Ps[pass][ntt][ri]);
                    const unsigned int part = __shfl_xor(hh, 1);
                    if (!(lane & 1)) {
                        const int nl = lg * 4 + ri;
                        const int off = ((h * 4 + mt) * 2 + (m >> 5)) * 1024
                                      + (nl + 16 * ((m & 31) >> 3)) * 16 + (m & 7) * 2;
                        *(unsigned int*)(Pr + off) = hh | (part << 16);
                    }
                }
            }
        }
    }
    __syncthreads();

    // ---- Phase 3: PV (MFMA) -> u-frags in XU; proj-W loads hoisted here ----
    bf16x8 pwh[4], pwl[4];
    {
        #pragma unroll
        for (int ks = 0; ks < 4; ++ks) {   // drain at phase-3 end barrier
            pwh[ks] = *(const bf16x8*)(g_wp_hi + (wid * 4 + ks) * 512 + lane * 8);
            pwl[ks] = *(const bf16x8*)(g_wp_lo + (wid * 4 + ks) * 512 + lane * 8);
        }
        const int h = wid >> 1, dt = wid & 1;
        bf16x8 vh[2];
        #pragma unroll
        for (int ks = 0; ks < 2; ++ks)
            vh[ks] = *(const bf16x8*)(Vr + ((h * 2 + dt) * 2 + ks) * 1024 + lane * 16);
        const int c = h * 32 + dt * 16 + lr;   // output channel
        #pragma unroll
        for (int mt = 0; mt < 4; ++mt) {
            f32x4 a = fz;
            #pragma unroll
            for (int ks = 0; ks < 2; ++ks) {
                const bf16x8 ph = *(const bf16x8*)(Pr + ((h * 4 + mt) * 2 + ks) * 1024
                                                      + lane * 16);
                a = mfma16(ph, vh[ks], a);
            }
            #pragma unroll
            for (int ri = 0; ri < 4; ++ri) {
                const unsigned int hh = (unsigned int)bf16_rne(a[ri]);
                const unsigned int part = __shfl_xor(hh, 1);
                if (!(lane & 1)) {
                    const int n = mt * 16 + lg * 4 + ri;
                    unsigned char* p = XU + (mt * 4 + (c >> 5)) * 1024
                                     + idx16(n & 15, (c & 31) >> 3, c >> 5) * 16
                                     + (c & 7) * 2;
                    *(unsigned int*)p = hh | (part << 16);
                }
            }
        }
    }
    __syncthreads();

    // ---- Phase 4: proj GEMM; A = u_hi, B = pw (already in regs); store ----
    {
        const int o = wid * 16 + lr;
        f32x4 acc[4];
        #pragma unroll
        for (int mt = 0; mt < 4; ++mt) acc[mt] = fz;
        #pragma unroll
        for (int ks = 0; ks < 4; ++ks) {
            #pragma unroll
            for (int mt = 0; mt < 4; ++mt) {
                const bf16x8 ah = *(const bf16x8*)(XU + (mt * 4 + ks) * 1024
                                                      + idx16(lr, lg, ks) * 16);
                acc[mt] = mfma16(ah, pwl[ks], acc[mt]);
                acc[mt] = mfma16(ah, pwh[ks], acc[mt]);
            }
        }
        const float pb = proj_b[o];
        float* orow = out + (size_t)blk * (N * C);
        #pragma unroll
        for (int mt = 0; mt < 4; ++mt) {
            #pragma unroll
            for (int ri = 0; ri < 4; ++ri) {
                const int n = mt * 16 + lg * 4 + ri;
                if (n < N) orow[n * C + o] = acc[mt][ri] + pb;
            }
        }
    }
}

extern "C" void kernel_launch(void* const* d_in, const int* in_sizes, int n_in,
                              void* d_out, int out_size, void* d_ws, size_t ws_size,
                              hipStream_t stream) {
    const float* x       = (const float*)d_in[0];
    const float* qkv_w   = (const float*)d_in[1];
    const float* proj_w  = (const float*)d_in[2];
    const float* proj_b  = (const float*)d_in[3];
    const float* table   = (const float*)d_in[4];
    const float* mask    = (const float*)d_in[5];
    const int*   pos_idx = (const int*)d_in[6];
    float* out = (float*)d_out;
    (void)d_ws; (void)ws_size;

    const int B  = in_sizes[0] / (N * C);       // element counts
    const int nW = in_sizes[5] / (N * N);

    // comb fill needs nW*4*4*4*64 threads (4.19M at nW=1024)
    const int prep_blocks = (nW * 4 * 4 * 4 * 64 + 255) / 256;
    prep<<<prep_blocks, 256, 0, stream>>>(qkv_w, proj_w, table, pos_idx, mask, nW);
    win_attn<<<B, NT, 0, stream>>>(x, proj_b, out, nW);
}

// Round 6
// 509.506 us; speedup vs baseline: 1.2137x; 1.2137x over previous
//
#include <hip/hip_runtime.h>
#include <math.h>

// WindowAttention fused kernel, round 6.
// vs round 5 (357us/dispatch, MfmaUtil 18.6, VALU 42, FETCH 455MB):
// - Weights bf16 hi-ONLY (W rounding adds ~9e-4 abs error vs 0.0156 existing;
//   negligible in quadrature). MFMAs/wave 144 -> 80; weight loads/regs halved.
// - comb (67MB, thrashed L3) split into maskf (16.7MB frag-order, L3-friendly)
//   + biasf (64KB, L2-resident). Same coalesced float4 phase-2 loads.
// - SCALE folded into W_q rows during prep.
//
// Fragment conventions (sigma-consistent A/B slot->k maps, D per m89):
//   A: row = lane&15, slot(g=lane>>4, j) -> k = 8g+j
//   B: col = lane&15, same slot map
//   D: col = lane&15, row = 4*(lane>>4)+reg
// Unit = 64 lanes x 16B = 1KB.
//
// LDS (65536 B): XU 16K (x-frags -> u-frags) | Qr 16K (q) | Kr 16K (k) |
//                Vr 16K (v-frags); P-frags overwrite Qr+Kr.

namespace {
constexpr int N  = 49;
constexpr int C  = 128;
constexpr int NT = 512;
constexpr int NWMAX = 1024;
constexpr float SCALE = 0.17677669529663687f;  // 32^-0.5

typedef short bf16x8 __attribute__((ext_vector_type(8)));
typedef float f32x4  __attribute__((ext_vector_type(4)));
}

// ---- static device storage for block-invariant data ----
__device__ __align__(16) ushort g_wq[24 * 4 * 512];      //  96 KB qkv W hi-frags (q pre-scaled)
__device__ __align__(16) ushort g_wp[8 * 4 * 512];       //  32 KB proj W hi-frags
// biasf[h][mt][ntt][lane][ri] = pos_bias in frag order (m>=49 -> 0)
__device__ __align__(16) float  g_biasf[4 * 4 * 4 * 256];          // 64 KB
// maskf[w][mt][ntt][lane][ri] = shift mask in frag order (m>=49 -> -1e30)
__device__ __align__(16) float  g_maskf[NWMAX * 4 * 4 * 256];      // 16.8 MB

__device__ __forceinline__ ushort bf16_rne(float f) {
    unsigned int u = __builtin_bit_cast(unsigned int, f);
    unsigned int r = u + 0x7FFFu + ((u >> 16) & 1u);
    return (ushort)(r >> 16);
}
__device__ __forceinline__ f32x4 mfma16(bf16x8 a, bf16x8 b, f32x4 c) {
    return __builtin_amdgcn_mfma_f32_16x16x32_bf16(a, b, c, 0, 0, 0);
}
// 16B-slot index within a 1KB unit, XOR-rotate swizzled (phase-0 write spread).
__device__ __forceinline__ int idx16(int row, int g, int ks) {
    return ((row + 4 * g + ks) & 15) + 16 * g;
}

// ---- prep kernel: block-invariant conversions ----
__global__ void prep(const float* __restrict__ qkv_w, const float* __restrict__ proj_w,
                     const float* __restrict__ table, const int* __restrict__ pos_index,
                     const float* __restrict__ mask, int nW)
{
    const int i = blockIdx.x * 256 + threadIdx.x;
    if (i < 24 * 4 * 512) {   // qkv B-frags (hi only, q rows pre-scaled)
        const int unit = i >> 9, sl = i & 511;
        const int nt = unit >> 2, ks = unit & 3;
        const int lane = sl >> 3, j = sl & 7;
        const int o = nt * 16 + (lane & 15);
        float w = qkv_w[o * C + ks * 32 + (lane >> 4) * 8 + j];
        if (o < 128) w *= SCALE;   // q section
        g_wq[i] = bf16_rne(w);
    }
    if (i < 8 * 4 * 512) {    // proj B-frags (hi only)
        const int unit = i >> 9, sl = i & 511;
        const int nt = unit >> 2, ks = unit & 3;
        const int lane = sl >> 3, j = sl & 7;
        const float w = proj_w[(nt * 16 + (lane & 15)) * C + ks * 32 + (lane >> 4) * 8 + j];
        g_wp[i] = bf16_rne(w);
    }
    if (i < 4 * 4 * 4 * 64) { // biasf: one thread per float4 over ri
        const int lane = i & 63;
        const int ntt  = (i >> 6) & 3;
        const int mt   = (i >> 8) & 3;
        const int h    = i >> 10;
        const int m    = ntt * 16 + (lane & 15);
        float vv[4];
        #pragma unroll
        for (int ri = 0; ri < 4; ++ri) {
            const int n0 = mt * 16 + (lane >> 4) * 4 + ri;
            const int n  = n0 > 48 ? 48 : n0;
            vv[ri] = (m < 49) ? table[pos_index[n * 49 + m] * 4 + h] : 0.f;
        }
        *((float4*)g_biasf + i) = make_float4(vv[0], vv[1], vv[2], vv[3]);
    }
    const int NM4 = nW * 4 * 4 * 64;   // maskf: one thread per float4 over ri
    if (i < NM4) {
        const int lane = i & 63;
        const int ntt  = (i >> 6) & 3;
        const int mt   = (i >> 8) & 3;
        const int w    = i >> 10;
        const int m    = ntt * 16 + (lane & 15);
        float vv[4];
        #pragma unroll
        for (int ri = 0; ri < 4; ++ri) {
            const int n0 = mt * 16 + (lane >> 4) * 4 + ri;
            const int n  = n0 > 48 ? 48 : n0;
            vv[ri] = (m < 49) ? mask[w * 2401 + n * 49 + m] : -1e30f;
        }
        *((float4*)g_maskf + i) = make_float4(vv[0], vv[1], vv[2], vv[3]);
    }
}

__device__ __forceinline__ void load_wq(bf16x8* bh, int nt, int lane) {
    #pragma unroll
    for (int ks = 0; ks < 4; ++ks)
        bh[ks] = *(const bf16x8*)(g_wq + (nt * 4 + ks) * 512 + lane * 8);
}

// One qkv column-tile step: 16 ds_read_b128 + 16 MFMA + scatter to q/k/v frags.
__device__ __forceinline__ void qkv_step(
    int nt, const bf16x8* bh,
    const unsigned char* XU, unsigned char* Qr, unsigned char* Kr, unsigned char* Vr,
    int lane, int lr, int lg)
{
    const f32x4 fz = {0.f, 0.f, 0.f, 0.f};
    f32x4 acc[4] = {fz, fz, fz, fz};
    #pragma unroll
    for (int ks = 0; ks < 4; ++ks) {
        #pragma unroll
        for (int mt = 0; mt < 4; ++mt) {
            const bf16x8 ah = *(const bf16x8*)(XU + (mt * 4 + ks) * 1024
                                                  + idx16(lr, lg, ks) * 16);
            acc[mt] = mfma16(ah, bh[ks], acc[mt]);
        }
    }
    const int o   = nt * 16 + lr;
    const int sec = o >> 7;          // 0=q 1=k 2=v (wave-uniform)
    const int h   = (o >> 5) & 3;
    const int d   = o & 31;
    #pragma unroll
    for (int mt = 0; mt < 4; ++mt) {
        unsigned int hh[4];
        #pragma unroll
        for (int ri = 0; ri < 4; ++ri)
            hh[ri] = (unsigned int)bf16_rne(acc[mt][ri]);
        if (sec <= 1) {
            unsigned char* ubase = (sec == 0 ? Qr : Kr) + (h * 4 + mt) * 1024;
            #pragma unroll
            for (int ri = 0; ri < 4; ++ri) {
                const unsigned int part = __shfl_xor(hh[ri], 1);
                if (!(lane & 1)) {
                    const int n = mt * 16 + lg * 4 + ri;
                    *(unsigned int*)(ubase + ((n & 15) + 16 * (d >> 3)) * 16
                                           + (d & 7) * 2) = hh[ri] | (part << 16);
                }
            }
        } else {
            #pragma unroll
            for (int rp = 0; rp < 2; ++rp) {   // pack (ri, ri+1): adjacent k=n
                const int n = mt * 16 + lg * 4 + rp * 2;
                const int u = (h * 2 + (d >> 4)) * 2 + (n >> 5);
                *(unsigned int*)(Vr + u * 1024 + ((d & 15) + 16 * ((n & 31) >> 3)) * 16
                                    + (n & 7) * 2) = hh[rp * 2] | (hh[rp * 2 + 1] << 16);
            }
        }
    }
}

__global__ __launch_bounds__(NT, 4) void win_attn(
    const float* __restrict__ x,         // [B,49,128]
    const float* __restrict__ proj_b,    // [128]
    float* __restrict__ out,             // [B,49,128]
    int nW)
{
    __shared__ __align__(16) unsigned char smem[65536];
    unsigned char* const XU = smem;            // 16KB x-frags -> u-frags
    unsigned char* const Qr = smem + 16384;    // 16KB q-frags
    unsigned char* const Kr = smem + 32768;    // 16KB k-frags
    unsigned char* const Vr = smem + 49152;    // 16KB v-frags
    unsigned char* const Pr = smem + 16384;    // 32KB P-frags (over Qr+Kr)

    const int tid  = threadIdx.x;
    const int blk  = blockIdx.x;
    const int lane = tid & 63;
    const int wid  = tid >> 6;
    const int lr   = lane & 15;
    const int lg   = lane >> 4;
    const f32x4 fz = {0.f, 0.f, 0.f, 0.f};

    // ---- Phase 0: x -> A-frags (bf16 hi), rows 49..63 zero ----
    {
        const float* xb = x + (size_t)blk * (N * C);
        #pragma unroll
        for (int it = 0; it < 2; ++it) {
            const int slot = tid + it * NT;   // (n 0..63) x (chunk 0..15)
            const int n  = slot >> 4;
            const int cc = slot & 15;
            const int s  = cc >> 2;           // ks
            const int g  = cc & 3;            // k-group
            unsigned int h32[4];
            if (n < N) {
                const float4 f0 = *(const float4*)(xb + n * C + cc * 8);
                const float4 f1 = *(const float4*)(xb + n * C + cc * 8 + 4);
                const float f[8] = {f0.x, f0.y, f0.z, f0.w, f1.x, f1.y, f1.z, f1.w};
                #pragma unroll
                for (int j = 0; j < 4; ++j)
                    h32[j] = (unsigned int)bf16_rne(f[2*j])
                           | ((unsigned int)bf16_rne(f[2*j+1]) << 16);
            } else {
                #pragma unroll
                for (int j = 0; j < 4; ++j) h32[j] = 0u;
            }
            unsigned char* p = XU + ((n >> 4) * 4 + s) * 1024 + idx16(n & 15, g, s) * 16;
            *(uint4*)p = make_uint4(h32[0], h32[1], h32[2], h32[3]);
        }
    }
    // issue t=0 weight-frag loads before the barrier (overlap with staging)
    bf16x8 bhA[4], bhB[4];
    load_wq(bhA, wid, lane);
    __syncthreads();

    // ---- Phase 1: qkv GEMM, software-pipelined over 3 column-tiles ----
    load_wq(bhB, wid + 8, lane);                      // prefetch t=1
    qkv_step(wid,      bhA, XU, Qr, Kr, Vr, lane, lr, lg);
    load_wq(bhA, wid + 16, lane);                     // prefetch t=2
    qkv_step(wid + 8,  bhB, XU, Qr, Kr, Vr, lane, lr, lg);
    qkv_step(wid + 16, bhA, XU, Qr, Kr, Vr, lane, lr, lg);
    __syncthreads();

    // ---- Phase 2: scores (MFMA) + maskf/biasf + in-reg softmax ----
    float Ps[2][4][4];
    {
        const float* mbase = g_maskf + (size_t)(blk % nW) * (4 * 4 * 256);
        #pragma unroll
        for (int pass = 0; pass < 2; ++pass) {
            const int cb = wid + pass * 8;   // (head, row-tile)
            const int h = cb >> 2, mt = cb & 3;
            float4 cv[4];
            #pragma unroll
            for (int ntt = 0; ntt < 4; ++ntt) {
                const float4 mv = *(const float4*)(mbase + (mt * 4 + ntt) * 256 + lane * 4);
                const float4 bv = *(const float4*)(g_biasf + ((h * 4 + mt) * 4 + ntt) * 256
                                                           + lane * 4);
                cv[ntt] = make_float4(mv.x + bv.x, mv.y + bv.y, mv.z + bv.z, mv.w + bv.w);
            }
            const bf16x8 qh = *(const bf16x8*)(Qr + (h * 4 + mt) * 1024 + lane * 16);
            f32x4 S[4];
            #pragma unroll
            for (int ntt = 0; ntt < 4; ++ntt) {
                const bf16x8 kh = *(const bf16x8*)(Kr + (h * 4 + ntt) * 1024 + lane * 16);
                S[ntt] = mfma16(qh, kh, fz);
            }
            #pragma unroll
            for (int ntt = 0; ntt < 4; ++ntt) {
                S[ntt][0] += cv[ntt].x;
                S[ntt][1] += cv[ntt].y;
                S[ntt][2] += cv[ntt].z;
                S[ntt][3] += cv[ntt].w;
            }
            #pragma unroll
            for (int ri = 0; ri < 4; ++ri) {
                float mx = fmaxf(fmaxf(S[0][ri], S[1][ri]), fmaxf(S[2][ri], S[3][ri]));
                mx = fmaxf(mx, __shfl_xor(mx, 1));
                mx = fmaxf(mx, __shfl_xor(mx, 2));
                mx = fmaxf(mx, __shfl_xor(mx, 4));
                mx = fmaxf(mx, __shfl_xor(mx, 8));
                float sm = 0.f;
                #pragma unroll
                for (int ntt = 0; ntt < 4; ++ntt) {
                    const float e = __expf(S[ntt][ri] - mx);
                    Ps[pass][ntt][ri] = e;
                    sm += e;
                }
                sm += __shfl_xor(sm, 1);
                sm += __shfl_xor(sm, 2);
                sm += __shfl_xor(sm, 4);
                sm += __shfl_xor(sm, 8);
                const float pinv = 1.f / sm;   // fold 1/sum into P
                #pragma unroll
                for (int ntt = 0; ntt < 4; ++ntt) Ps[pass][ntt][ri] *= pinv;
            }
        }
    }
    __syncthreads();   // q/k reads done before P overwrites

    // ---- Phase 2b: write normalized P as A-frags over Qr+Kr ----
    {
        #pragma unroll
        for (int pass = 0; pass < 2; ++pass) {
            const int cb = wid + pass * 8;
            const int h = cb >> 2, mt = cb & 3;
            #pragma unroll
            for (int ntt = 0; ntt < 4; ++ntt) {
                const int m = ntt * 16 + lr;   // k-index
                #pragma unroll
                for (int ri = 0; ri < 4; ++ri) {
                    const unsigned int hh = (unsigned int)bf16_rne(Ps[pass][ntt][ri]);
                    const unsigned int part = __shfl_xor(hh, 1);
                    if (!(lane & 1)) {
                        const int nl = lg * 4 + ri;
                        const int off = ((h * 4 + mt) * 2 + (m >> 5)) * 1024
                                      + (nl + 16 * ((m & 31) >> 3)) * 16 + (m & 7) * 2;
                        *(unsigned int*)(Pr + off) = hh | (part << 16);
                    }
                }
            }
        }
    }
    __syncthreads();

    // ---- Phase 3: PV (MFMA) -> u-frags in XU; proj-W loads hoisted here ----
    bf16x8 pwh[4];
    {
        #pragma unroll
        for (int ks = 0; ks < 4; ++ks)   // drain at phase-3 end barrier
            pwh[ks] = *(const bf16x8*)(g_wp + (wid * 4 + ks) * 512 + lane * 8);
        const int h = wid >> 1, dt = wid & 1;
        bf16x8 vh[2];
        #pragma unroll
        for (int ks = 0; ks < 2; ++ks)
            vh[ks] = *(const bf16x8*)(Vr + ((h * 2 + dt) * 2 + ks) * 1024 + lane * 16);
        const int c = h * 32 + dt * 16 + lr;   // output channel
        #pragma unroll
        for (int mt = 0; mt < 4; ++mt) {
            f32x4 a = fz;
            #pragma unroll
            for (int ks = 0; ks < 2; ++ks) {
                const bf16x8 ph = *(const bf16x8*)(Pr + ((h * 4 + mt) * 2 + ks) * 1024
                                                      + lane * 16);
                a = mfma16(ph, vh[ks], a);
            }
            #pragma unroll
            for (int ri = 0; ri < 4; ++ri) {
                const unsigned int hh = (unsigned int)bf16_rne(a[ri]);
                const unsigned int part = __shfl_xor(hh, 1);
                if (!(lane & 1)) {
                    const int n = mt * 16 + lg * 4 + ri;
                    unsigned char* p = XU + (mt * 4 + (c >> 5)) * 1024
                                     + idx16(n & 15, (c & 31) >> 3, c >> 5) * 16
                                     + (c & 7) * 2;
                    *(unsigned int*)p = hh | (part << 16);
                }
            }
        }
    }
    __syncthreads();

    // ---- Phase 4: proj GEMM; A = u_hi, B = pwh (in regs); + bias; store ----
    {
        const int o = wid * 16 + lr;
        f32x4 acc[4];
        #pragma unroll
        for (int mt = 0; mt < 4; ++mt) acc[mt] = fz;
        #pragma unroll
        for (int ks = 0; ks < 4; ++ks) {
            #pragma unroll
            for (int mt = 0; mt < 4; ++mt) {
                const bf16x8 ah = *(const bf16x8*)(XU + (mt * 4 + ks) * 1024
                                                      + idx16(lr, lg, ks) * 16);
                acc[mt] = mfma16(ah, pwh[ks], acc[mt]);
            }
        }
        const float pb = proj_b[o];
        float* orow = out + (size_t)blk * (N * C);
        #pragma unroll
        for (int mt = 0; mt < 4; ++mt) {
            #pragma unroll
            for (int ri = 0; ri < 4; ++ri) {
                const int n = mt * 16 + lg * 4 + ri;
                if (n < N) orow[n * C + o] = acc[mt][ri] + pb;
            }
        }
    }
}

extern "C" void kernel_launch(void* const* d_in, const int* in_sizes, int n_in,
                              void* d_out, int out_size, void* d_ws, size_t ws_size,
                              hipStream_t stream) {
    const float* x       = (const float*)d_in[0];
    const float* qkv_w   = (const float*)d_in[1];
    const float* proj_w  = (const float*)d_in[2];
    const float* proj_b  = (const float*)d_in[3];
    const float* table   = (const float*)d_in[4];
    const float* mask    = (const float*)d_in[5];
    const int*   pos_idx = (const int*)d_in[6];
    float* out = (float*)d_out;
    (void)d_ws; (void)ws_size;

    const int B  = in_sizes[0] / (N * C);       // element counts
    const int nW = in_sizes[5] / (N * N);

    // maskf fill needs nW*4*4*64 threads (1.05M at nW=1024)
    const int prep_blocks = (nW * 4 * 4 * 64 + 255) / 256;
    prep<<<prep_blocks, 256, 0, stream>>>(qkv_w, proj_w, table, pos_idx, mask, nW);
    win_attn<<<B, NT, 0, stream>>>(x, proj_b, out, nW);
}